// Round 4
// baseline (17323.470 us; speedup 1.0000x reference)
//
#include <hip/hip_runtime.h>

#define B_ 512
#define N_ 256
#define D_ 256
#define NEGINF (-1e30)

typedef float v4f __attribute__((ext_vector_type(4)));

// ---------------- transpose: out[c][r] = in[r][c], in is R x C ----------------
__global__ void transpose_k(const float* __restrict__ in, float* __restrict__ out,
                            int R, int C) {
  __shared__ float tile[32][33];
  int rb = blockIdx.y * 32, cb = blockIdx.x * 32;
  int tx = threadIdx.x, ty = threadIdx.y;  // block (32,8)
  for (int i = ty; i < 32; i += 8) {
    int r = rb + i, c = cb + tx;
    if (r < R && c < C) tile[i][tx] = in[r * C + c];
  }
  __syncthreads();
  for (int i = ty; i < 32; i += 8) {
    int c = cb + i, r = rb + tx;
    if (r < R && c < C) out[c * R + r] = tile[tx][i];
  }
}

// ---- packW: w (768x256 row-major) -> wave-packed v4f layout -------------------
// dst[((w16*16 + k)*3 + g)*64 + l], w16=o>>4, k=c4&15, l=4*(o&15)+(c4>>4), j=g*256+o
__global__ __launch_bounds__(256) void packW_k(const float* __restrict__ in,
                                               float* __restrict__ out) {
  int idx = blockIdx.x * 256 + threadIdx.x;  // 49152 v4f
  int j = idx >> 6, c4 = idx & 63;
  int g = j >> 8, o = j & 255;
  int w16 = o >> 4, k = c4 & 15, l = 4 * (o & 15) + (c4 >> 4);
  ((v4f*)out)[((w16 * 16 + k) * 3 + g) * 64 + l] = ((const v4f*)in)[idx];
}

// ---- Wqk[c][e] = sum_d wk[d][c]*wq[d][e] (fp64), packed; bqk[c]=sum wk[d][c]*bq[d]
__global__ __launch_bounds__(256) void wqk_k(const float* __restrict__ wk,
                                             const float* __restrict__ wq,
                                             const float* __restrict__ bq,
                                             double* __restrict__ WqkP,
                                             double* __restrict__ bqk) {
  int c = blockIdx.x, e = threadIdx.x;
  double acc = 0.0;
  for (int dd = 0; dd < 256; ++dd)
    acc += (double)wk[dd * 256 + c] * (double)wq[dd * 256 + e];
  int w16 = c >> 4, k2 = (e >> 1) & 31, l = 4 * (c & 15) + (e >> 6), comp = e & 1;
  WqkP[(size_t)(((w16 * 32) + k2) * 64 + l) * 2 + comp] = acc;
  if (e == 0) {
    double s = 0.0;
    for (int dd = 0; dd < 256; ++dd) s += (double)wk[dd * 256 + c] * (double)bq[dd];
    bqk[c] = s;
  }
}

// ---- encP: wave-packed per-row layout: eP4[b][(w16*16+k)*64+l] ----------------
// n = w16*16 + (l>>2), c4 = (l&3)*16 + k
__global__ __launch_bounds__(256) void encp_k(const float* __restrict__ enc,
                                              float* __restrict__ encP) {
  int b = blockIdx.y;
  int idx = blockIdx.x * 256 + threadIdx.x;  // 16384 v4f per b
  int l = idx & 63, rest = idx >> 6;
  int k = rest & 15, w16 = rest >> 4;
  int n = w16 * 16 + (l >> 2), c4 = (l & 3) * 16 + k;
  ((v4f*)encP)[(size_t)b * 16384 + idx] =
      *(const v4f*)(enc + (size_t)b * 65536 + n * 256 + c4 * 4);
}

// ---- Gi[(b*256+n)*768 + j] = b_ih[j] + sum_c w_ih[j][c]*enc[b][n][c]  (fp64) --
__global__ __launch_bounds__(768) void gi_k(const float* __restrict__ enc,
                                            const float* __restrict__ wihT,
                                            const float* __restrict__ b_ih,
                                            double* __restrict__ Gi) {
  int b = blockIdx.x, j = threadIdx.x;
  __shared__ float encS[32][256];
  const float* encB = enc + (size_t)b * 65536;
  double bias = (double)b_ih[j];
  for (int n0 = 0; n0 < 256; n0 += 32) {
    __syncthreads();
    for (int i = j; i < 2048; i += 768)
      ((float4*)encS)[i] = ((const float4*)(encB + n0 * 256))[i];
    __syncthreads();
    double acc[32];
#pragma unroll
    for (int jj = 0; jj < 32; ++jj) acc[jj] = bias;
    for (int c0 = 0; c0 < 256; c0 += 4) {
      double w0 = (double)wihT[(c0 + 0) * 768 + j];
      double w1 = (double)wihT[(c0 + 1) * 768 + j];
      double w2 = (double)wihT[(c0 + 2) * 768 + j];
      double w3 = (double)wihT[(c0 + 3) * 768 + j];
#pragma unroll
      for (int jj = 0; jj < 32; ++jj) {
        const float4 e = *(const float4*)&encS[jj][c0];
        acc[jj] += w0 * (double)e.x + w1 * (double)e.y + w2 * (double)e.z + w3 * (double)e.w;
      }
    }
#pragma unroll
    for (int jj = 0; jj < 32; ++jj)
      Gi[((size_t)b * 256 + n0 + jj) * 768 + j] = acc[jj];
  }
}

// ---------------- persistent decode: 2 rows/block, 1024 thr, shfl-reduce ------
template <bool USE_GI>
__global__ __launch_bounds__(1024, 4) void decode_k(
    const float* __restrict__ enc, const float* __restrict__ init_token,
    const float* __restrict__ b_ih, const float* __restrict__ b_hh,
    const float* __restrict__ wihP, const float* __restrict__ whhP,
    const double* __restrict__ WqkP, const double* __restrict__ bqk,
    const float* __restrict__ encP, const double* __restrict__ Gi,
    float* __restrict__ out) {
  const int tid = threadIdx.x;
  const int WV = tid >> 6;        // wave 0..15
  const int LN = tid & 63;        // lane
  const int O = WV * 16 + (LN >> 2);  // output index 0..255
  const int S = LN & 3;           // slice 0..3  (c-range [64S, 64S+64))
  const int ROW = S >> 1;         // row this lane finalizes
  const int b0 = blockIdx.x * 2;

  __shared__ alignas(16) double hS[2][2][D_];   // [pingpong][row][d]
  __shared__ alignas(16) double xS[2][D_];      // Tier-B x (and init scratch)
  __shared__ alignas(16) double giS[2][768];    // Tier-A gathered Gi rows
  __shared__ alignas(16) double qs[2][D_];
  __shared__ double lg[2][N_];
  __shared__ unsigned char maskS[2][N_];
  __shared__ double redA[16][2], redB[16][2], redC[16][2];
  __shared__ int redI[16][2];

  const float* encB0 = enc + (size_t)b0 * 65536;
  const float* encB1 = encB0 + 65536;
  const v4f* eP0 = (const v4f*)encP + (size_t)b0 * 16384;
  const v4f* eP1 = eP0 + 16384;
  const v4f* wh4 = (const v4f*)whhP;
  const v4f* wi4 = (const v4f*)wihP;
  const double2* Wp2 = (const double2*)WqkP;

  // ---------------- init ----------------
  if (tid < 256) xS[0][tid] = (double)init_token[tid];
  {
    double p0 = 0.0, p1 = 0.0;
    const float* e0 = encB0 + (size_t)(S * 64) * 256 + O;
    const float* e1 = encB1 + (size_t)(S * 64) * 256 + O;
#pragma unroll 4
    for (int n = 0; n < 64; ++n) { p0 += (double)e0[n * 256]; p1 += (double)e1[n * 256]; }
    p0 += __shfl_xor(p0, 1); p0 += __shfl_xor(p0, 2);
    p1 += __shfl_xor(p1, 1); p1 += __shfl_xor(p1, 2);
    if (S == 0) { hS[0][0][O] = p0 * (1.0 / 256.0); hS[0][1][O] = p1 * (1.0 / 256.0); }
  }
  if (tid < 256) { maskS[0][tid] = 1; maskS[1][tid] = 1; }
  __syncthreads();
  if (USE_GI) {
    // gi for x = init_token (same for both rows)
    double a0 = 0, a1 = 0, a2 = 0;
#pragma unroll 2
    for (int k = 0; k < 16; ++k) {
      int wb = ((WV * 16 + k) * 3) * 64 + LN;
      v4f ar = wi4[wb], az = wi4[wb + 64], an = wi4[wb + 128];
      const double* xp = &xS[0][S * 64 + 4 * k];
#pragma unroll
      for (int i = 0; i < 4; ++i) {
        a0 += (double)ar[i] * xp[i];
        a1 += (double)az[i] * xp[i];
        a2 += (double)an[i] * xp[i];
      }
    }
    a0 += __shfl_xor(a0, 1); a0 += __shfl_xor(a0, 2);
    a1 += __shfl_xor(a1, 1); a1 += __shfl_xor(a1, 2);
    a2 += __shfl_xor(a2, 1); a2 += __shfl_xor(a2, 2);
    if (S == 0) {
      double v0 = a0 + (double)b_ih[O];
      double v1 = a1 + (double)b_ih[256 + O];
      double v2 = a2 + (double)b_ih[512 + O];
      giS[0][O] = v0;        giS[1][O] = v0;
      giS[0][256 + O] = v1;  giS[1][256 + O] = v1;
      giS[0][512 + O] = v2;  giS[1][512 + O] = v2;
    }
  } else {
    if (tid < 256) xS[1][tid] = xS[0][tid];
  }
  __syncthreads();

  int cur = 0;
  for (int t = 0; t < N_; ++t) {
    const int nxt = cur ^ 1;
    // ---- P1: GRU ----
    double ghr0 = 0, ghz0 = 0, ghn0 = 0, ghr1 = 0, ghz1 = 0, ghn1 = 0;
    double air0 = 0, aiz0 = 0, ain0 = 0, air1 = 0, aiz1 = 0, ain1 = 0;
#pragma unroll 2
    for (int k = 0; k < 16; ++k) {
      int wb = ((WV * 16 + k) * 3) * 64 + LN;
      v4f br = wh4[wb], bz = wh4[wb + 64], bn = wh4[wb + 128];
      int c = S * 64 + 4 * k;
      const double* h0 = &hS[cur][0][c];
      const double* h1 = &hS[cur][1][c];
#pragma unroll
      for (int i = 0; i < 4; ++i) {
        double wr = (double)br[i], wz = (double)bz[i], wn = (double)bn[i];
        ghr0 += wr * h0[i]; ghz0 += wz * h0[i]; ghn0 += wn * h0[i];
        ghr1 += wr * h1[i]; ghz1 += wz * h1[i]; ghn1 += wn * h1[i];
      }
      if (!USE_GI) {
        v4f ar = wi4[wb], az = wi4[wb + 64], an = wi4[wb + 128];
        const double* x0 = &xS[0][c];
        const double* x1 = &xS[1][c];
#pragma unroll
        for (int i = 0; i < 4; ++i) {
          double wr = (double)ar[i], wz = (double)az[i], wn = (double)an[i];
          air0 += wr * x0[i]; aiz0 += wz * x0[i]; ain0 += wn * x0[i];
          air1 += wr * x1[i]; aiz1 += wz * x1[i]; ain1 += wn * x1[i];
        }
      }
    }
    ghr0 += __shfl_xor(ghr0, 1); ghr0 += __shfl_xor(ghr0, 2);
    ghz0 += __shfl_xor(ghz0, 1); ghz0 += __shfl_xor(ghz0, 2);
    ghn0 += __shfl_xor(ghn0, 1); ghn0 += __shfl_xor(ghn0, 2);
    ghr1 += __shfl_xor(ghr1, 1); ghr1 += __shfl_xor(ghr1, 2);
    ghz1 += __shfl_xor(ghz1, 1); ghz1 += __shfl_xor(ghz1, 2);
    ghn1 += __shfl_xor(ghn1, 1); ghn1 += __shfl_xor(ghn1, 2);
    if (!USE_GI) {
      air0 += __shfl_xor(air0, 1); air0 += __shfl_xor(air0, 2);
      aiz0 += __shfl_xor(aiz0, 1); aiz0 += __shfl_xor(aiz0, 2);
      ain0 += __shfl_xor(ain0, 1); ain0 += __shfl_xor(ain0, 2);
      air1 += __shfl_xor(air1, 1); air1 += __shfl_xor(air1, 2);
      aiz1 += __shfl_xor(aiz1, 1); aiz1 += __shfl_xor(aiz1, 2);
      ain1 += __shfl_xor(ain1, 1); ain1 += __shfl_xor(ain1, 2);
    }
    {
      double gir, giz, gin;
      if (USE_GI) {
        gir = giS[ROW][O]; giz = giS[ROW][256 + O]; gin = giS[ROW][512 + O];
      } else {
        gir = (ROW ? air1 : air0) + (double)b_ih[O];
        giz = (ROW ? aiz1 : aiz0) + (double)b_ih[256 + O];
        gin = (ROW ? ain1 : ain0) + (double)b_ih[512 + O];
      }
      double hr_ = (ROW ? ghr1 : ghr0) + (double)b_hh[O];
      double hz_ = (ROW ? ghz1 : ghz0) + (double)b_hh[256 + O];
      double hn_ = (ROW ? ghn1 : ghn0) + (double)b_hh[512 + O];
      double rr = 1.0 / (1.0 + exp(-(gir + hr_)));
      double zz = 1.0 / (1.0 + exp(-(giz + hz_)));
      double nn = tanh(gin + rr * hn_);
      double hold = hS[cur][ROW][O];
      double hnew = (1.0 - zz) * nn + zz * hold;
      if ((S & 1) == 0) hS[nxt][ROW][O] = hnew;
    }
    __syncthreads();  // B1: h ready

    // ---- P2: qk = Wqk·h + bqk ----
    {
      double q0 = 0, q1 = 0;
#pragma unroll 4
      for (int k = 0; k < 32; ++k) {
        double2 wv = Wp2[(WV * 32 + k) * 64 + LN];
        int dd = S * 64 + 2 * k;
        q0 += wv.x * hS[nxt][0][dd] + wv.y * hS[nxt][0][dd + 1];
        q1 += wv.x * hS[nxt][1][dd] + wv.y * hS[nxt][1][dd + 1];
      }
      q0 += __shfl_xor(q0, 1); q0 += __shfl_xor(q0, 2);
      q1 += __shfl_xor(q1, 1); q1 += __shfl_xor(q1, 2);
      if (S == 0) { double bb = bqk[O]; qs[0][O] = q0 + bb; qs[1][O] = q1 + bb; }
    }
    __syncthreads();  // B2: qs ready

    // ---- P3: logits + wave argmax ----
    double lgv0, lgv1;
    {
      double p0 = 0, p1 = 0;
#pragma unroll 2
      for (int k = 0; k < 16; ++k) {
        int eb = (WV * 16 + k) * 64 + LN;
        v4f e0 = eP0[eb];
        v4f e1 = eP1[eb];
        int c = S * 64 + 4 * k;
        const double* qa = &qs[0][c];
        const double* qb = &qs[1][c];
#pragma unroll
        for (int i = 0; i < 4; ++i) {
          p0 += (double)e0[i] * qa[i];
          p1 += (double)e1[i] * qb[i];
        }
      }
      p0 += __shfl_xor(p0, 1); p0 += __shfl_xor(p0, 2);
      p1 += __shfl_xor(p1, 1); p1 += __shfl_xor(p1, 2);
      lgv0 = 0.0625 * p0; if (!maskS[0][O]) lgv0 = NEGINF;
      lgv1 = 0.0625 * p1; if (!maskS[1][O]) lgv1 = NEGINF;
      if (S == 0) { lg[0][O] = lgv0; lg[1][O] = lgv1; }
      double v0 = lgv0, v1 = lgv1;
      int i0 = O, i1 = O;
#pragma unroll
      for (int off = 1; off < 64; off <<= 1) {
        double t0 = __shfl_xor(v0, off); int ti0 = __shfl_xor(i0, off);
        if (t0 > v0 || (t0 == v0 && ti0 < i0)) { v0 = t0; i0 = ti0; }
        double t1 = __shfl_xor(v1, off); int ti1 = __shfl_xor(i1, off);
        if (t1 > v1 || (t1 == v1 && ti1 < i1)) { v1 = t1; i1 = ti1; }
      }
      if (LN == 0) { redA[WV][0] = v0; redI[WV][0] = i0; redA[WV][1] = v1; redI[WV][1] = i1; }
    }
    __syncthreads();  // B3: redA ready

    // ---- P4: final max/argmax (all threads), exp-sums, gather next x ----
    double m0 = -1e300, m1 = -1e300;
    int am0 = 0, am1 = 0;
#pragma unroll 4
    for (int w = 0; w < 16; ++w) {
      double va = redA[w][0]; int ia = redI[w][0];
      if (va > m0 || (va == m0 && ia < am0)) { m0 = va; am0 = ia; }
      double vb = redA[w][1]; int ib = redI[w][1];
      if (vb > m1 || (vb == m1 && ib < am1)) { m1 = vb; am1 = ib; }
    }
    {
      double e0 = (S == 0) ? exp(lgv0 - m0) : 0.0;
      double e1 = (S == 0) ? exp(lgv1 - m1) : 0.0;
      double s20 = e0 * (lgv0 - m0);
      double s21 = e1 * (lgv1 - m1);
#pragma unroll
      for (int off = 1; off < 64; off <<= 1) {
        e0 += __shfl_xor(e0, off);
        e1 += __shfl_xor(e1, off);
        s20 += __shfl_xor(s20, off);
        s21 += __shfl_xor(s21, off);
      }
      if (LN == 0) { redB[WV][0] = e0; redB[WV][1] = e1; redC[WV][0] = s20; redC[WV][1] = s21; }
    }
    if (USE_GI) {
      size_t g0 = ((size_t)b0 * 256 + am0) * 768;
      size_t g1 = ((size_t)(b0 + 1) * 256 + am1) * 768;
      if (tid < 768) giS[0][tid] = Gi[g0 + tid];
      int t2 = tid - 256;
      if (t2 >= 0 && t2 < 768) giS[1][t2] = Gi[g1 + t2];
    } else {
      if (tid < 512) {
        int r = tid >> 8, j = tid & 255;
        int am = r ? am1 : am0;
        int c4 = j >> 2;
        int vidx = ((am >> 4) * 16 + (c4 & 15)) * 64 + (4 * (am & 15) + (c4 >> 4));
        const float* ePr = r ? (const float*)eP1 : (const float*)eP0;
        xS[r][j] = (double)ePr[vidx * 4 + (j & 3)];
      }
    }
    __syncthreads();  // B4: redB/C + gathers ready

    // ---- P5: outputs + mask ----
    if (tid < 2) {
      int r = tid;
      double m = r ? m1 : m0;
      int am = r ? am1 : am0;
      double S1 = 0, S2 = 0;
#pragma unroll 4
      for (int w = 0; w < 16; ++w) { S1 += redB[w][r]; S2 += redC[w][r]; }
      double lS = log(S1);
      double logZ = m + lS;
      size_t row = (size_t)(b0 + r) * N_;
      out[row + t] = (float)am;
      out[(size_t)B_ * N_ + row + t] = (float)(lg[r][am] - logZ);
      out[2 * (size_t)B_ * N_ + row + t] = (float)(lS - S2 / S1);
      maskS[r][am] = 0;
    }
    __syncthreads();  // B5: mask/outputs done
    cur ^= 1;
  }
}

extern "C" void kernel_launch(void* const* d_in, const int* in_sizes, int n_in,
                              void* d_out, int out_size, void* d_ws, size_t ws_size,
                              hipStream_t stream) {
  const float* enc = (const float*)d_in[0];
  const float* init_token = (const float*)d_in[1];
  const float* w_ih = (const float*)d_in[2];
  const float* w_hh = (const float*)d_in[3];
  const float* b_ih = (const float*)d_in[4];
  const float* b_hh = (const float*)d_in[5];
  const float* wq = (const float*)d_in[6];
  const float* bq = (const float*)d_in[7];
  const float* wk = (const float*)d_in[8];
  const float* bk = (const float*)d_in[9];  // folded out by softmax shift-invariance
  (void)bk;
  float* out = (float*)d_out;
  char* wsb = (char*)d_ws;

  // ws layout (bytes)
  float* wihP = (float*)(wsb + 0);                 //    786,432
  float* whhP = (float*)(wsb + 786432);            //    786,432
  double* WqkP = (double*)(wsb + 1572864);         //    524,288
  double* bqk = (double*)(wsb + 2097152);          //      2,048
  float* encP = (float*)(wsb + 2099200);           // 134,217,728  (Tier-B end: 136,316,928)
  float* wihT = (float*)(wsb + 136316928);         //    786,432
  double* Gi = (double*)(wsb + 137103360);         // 805,306,368  (Tier-A end: 942,409,728)
  const bool useGi = ws_size >= 942409728ull;

  hipLaunchKernelGGL(packW_k, dim3(192), dim3(256), 0, stream, w_ih, wihP);
  hipLaunchKernelGGL(packW_k, dim3(192), dim3(256), 0, stream, w_hh, whhP);
  hipLaunchKernelGGL(wqk_k, dim3(256), dim3(256), 0, stream, wk, wq, bq, WqkP, bqk);
  hipLaunchKernelGGL(encp_k, dim3(64, 512), dim3(256), 0, stream, enc, encP);
  if (useGi) {
    hipLaunchKernelGGL(transpose_k, dim3(8, 24), dim3(32, 8), 0, stream, w_ih, wihT, 768, 256);
    hipLaunchKernelGGL(gi_k, dim3(512), dim3(768), 0, stream, enc, wihT, b_ih, Gi);
    hipLaunchKernelGGL(decode_k<true>, dim3(B_ / 2), dim3(1024), 0, stream, enc, init_token,
                       b_ih, b_hh, wihP, whhP, WqkP, bqk, encP, Gi, out);
  } else {
    hipLaunchKernelGGL(decode_k<false>, dim3(B_ / 2), dim3(1024), 0, stream, enc, init_token,
                       b_ih, b_hh, wihP, whhP, WqkP, bqk, encP, Gi, out);
  }
}

// Round 5
// 17231.529 us; speedup vs baseline: 1.0053x; 1.0053x over previous
//
#include <hip/hip_runtime.h>

#define B_ 512
#define N_ 256
#define D_ 256
#define NEGINF (-1e30)

// padded LDS index: slice bases 64 doubles apart get +1 double of pad ->
// banks {0,2,4,6} for S=0..3 instead of all bank 0.
#define PD(c) ((c) + ((c) >> 6))

typedef float v4f __attribute__((ext_vector_type(4)));

__device__ __forceinline__ v4f ntload4(const v4f* p) {
  return __builtin_nontemporal_load(p);
}

// ---- packW: w (768x256 row-major) -> wave-packed v4f layout -------------------
// dst[((w16*16 + k)*3 + g)*64 + l], w16=o>>4, k=c4&15, l=4*(o&15)+(c4>>4), j=g*256+o
__global__ __launch_bounds__(256) void packW_k(const float* __restrict__ in,
                                               float* __restrict__ out) {
  int idx = blockIdx.x * 256 + threadIdx.x;  // 49152 v4f
  int j = idx >> 6, c4 = idx & 63;
  int g = j >> 8, o = j & 255;
  int w16 = o >> 4, k = c4 & 15, l = 4 * (o & 15) + (c4 >> 4);
  ((v4f*)out)[((w16 * 16 + k) * 3 + g) * 64 + l] = ((const v4f*)in)[idx];
}

// ---- Wqk[c][e] = sum_d wk[d][c]*wq[d][e] (fp64), packed; bqk[c]=sum wk[d][c]*bq[d]
__global__ __launch_bounds__(256) void wqk_k(const float* __restrict__ wk,
                                             const float* __restrict__ wq,
                                             const float* __restrict__ bq,
                                             double* __restrict__ WqkP,
                                             double* __restrict__ bqk) {
  int c = blockIdx.x, e = threadIdx.x;
  double acc = 0.0;
  for (int dd = 0; dd < 256; ++dd)
    acc += (double)wk[dd * 256 + c] * (double)wq[dd * 256 + e];
  int w16 = c >> 4, k2 = (e >> 1) & 31, l = 4 * (c & 15) + (e >> 6), comp = e & 1;
  WqkP[(size_t)(((w16 * 32) + k2) * 64 + l) * 2 + comp] = acc;
  if (e == 0) {
    double s = 0.0;
    for (int dd = 0; dd < 256; ++dd) s += (double)wk[dd * 256 + c] * (double)bq[dd];
    bqk[c] = s;
  }
}

// ---- encP: wave-packed per-row layout: eP4[b][(w16*16+k)*64+l] ----------------
// n = w16*16 + (l>>2), c4 = (l&3)*16 + k
__global__ __launch_bounds__(256) void encp_k(const float* __restrict__ enc,
                                              float* __restrict__ encP) {
  int b = blockIdx.y;
  int idx = blockIdx.x * 256 + threadIdx.x;  // 16384 v4f per b
  int l = idx & 63, rest = idx >> 6;
  int k = rest & 15, w16 = rest >> 4;
  int n = w16 * 16 + (l >> 2), c4 = (l & 3) * 16 + k;
  ((v4f*)encP)[(size_t)b * 16384 + idx] =
      *(const v4f*)(enc + (size_t)b * 65536 + n * 256 + c4 * 4);
}

// ---------------- persistent decode: 2 rows/block, 1024 thr, shfl-reduce ------
__global__ __launch_bounds__(1024, 4) void decode_k(
    const float* __restrict__ enc, const float* __restrict__ init_token,
    const float* __restrict__ b_ih, const float* __restrict__ b_hh,
    const float* __restrict__ wihP, const float* __restrict__ whhP,
    const double* __restrict__ WqkP, const double* __restrict__ bqk,
    const float* __restrict__ encP, float* __restrict__ out) {
  const int tid = threadIdx.x;
  const int WV = tid >> 6;            // wave 0..15
  const int LN = tid & 63;            // lane
  const int O = WV * 16 + (LN >> 2);  // output index 0..255
  const int S = LN & 3;               // slice 0..3  (c-range [64S, 64S+64))
  const int ROW = S >> 1;             // row this lane finalizes
  const int b0 = blockIdx.x * 2;

  __shared__ alignas(16) double hS[2][2][260];  // [pingpong][row][PD(d)]
  __shared__ alignas(16) double xS[2][260];     // [row][PD(d)]
  __shared__ alignas(16) double qs[2][260];
  __shared__ double lg[2][N_];
  __shared__ unsigned char maskS[2][N_];
  __shared__ double redA[16][2], redB[16][2], redC[16][2];
  __shared__ int redI[16][2];

  const float* encB0 = enc + (size_t)b0 * 65536;
  const float* encB1 = encB0 + 65536;
  const v4f* eP0 = (const v4f*)encP + (size_t)b0 * 16384;
  const v4f* eP1 = eP0 + 16384;
  const v4f* wh4 = (const v4f*)whhP;
  const v4f* wi4 = (const v4f*)wihP;
  const double2* Wp2 = (const double2*)WqkP;

  // ---------------- init ----------------
  if (tid < 256) {
    double iv = (double)init_token[tid];
    xS[0][PD(tid)] = iv;
    xS[1][PD(tid)] = iv;
    maskS[0][tid] = 1;
    maskS[1][tid] = 1;
  }
  {
    double p0 = 0.0, p1 = 0.0;
    const float* e0 = encB0 + (size_t)(S * 64) * 256 + O;
    const float* e1 = encB1 + (size_t)(S * 64) * 256 + O;
#pragma unroll 4
    for (int n = 0; n < 64; ++n) { p0 += (double)e0[n * 256]; p1 += (double)e1[n * 256]; }
    p0 += __shfl_xor(p0, 1); p0 += __shfl_xor(p0, 2);
    p1 += __shfl_xor(p1, 1); p1 += __shfl_xor(p1, 2);
    if (S == 0) {
      hS[0][0][PD(O)] = p0 * (1.0 / 256.0);
      hS[0][1][PD(O)] = p1 * (1.0 / 256.0);
    }
  }
  __syncthreads();

  int cur = 0;
  for (int t = 0; t < N_; ++t) {
    const int nxt = cur ^ 1;
    // ---- P1: GRU (h-side + x-side), split-K over S, xor-combine ----
    double ghr0 = 0, ghz0 = 0, ghn0 = 0, ghr1 = 0, ghz1 = 0, ghn1 = 0;
    double air0 = 0, aiz0 = 0, ain0 = 0, air1 = 0, aiz1 = 0, ain1 = 0;
#pragma unroll 4
    for (int k = 0; k < 16; ++k) {
      int wb = ((WV * 16 + k) * 3) * 64 + LN;
      v4f br = wh4[wb], bz = wh4[wb + 64], bn = wh4[wb + 128];
      v4f ar = wi4[wb], az = wi4[wb + 64], an = wi4[wb + 128];
      int c = S * 64 + 4 * k;              // PD(c) = c + S within slice S
      const double* h0 = &hS[cur][0][c + S];
      const double* h1 = &hS[cur][1][c + S];
      const double* x0 = &xS[0][c + S];
      const double* x1 = &xS[1][c + S];
#pragma unroll
      for (int i = 0; i < 4; ++i) {
        double wr = (double)br[i], wz = (double)bz[i], wn = (double)bn[i];
        ghr0 += wr * h0[i]; ghz0 += wz * h0[i]; ghn0 += wn * h0[i];
        ghr1 += wr * h1[i]; ghz1 += wz * h1[i]; ghn1 += wn * h1[i];
        double vr = (double)ar[i], vz = (double)az[i], vn = (double)an[i];
        air0 += vr * x0[i]; aiz0 += vz * x0[i]; ain0 += vn * x0[i];
        air1 += vr * x1[i]; aiz1 += vz * x1[i]; ain1 += vn * x1[i];
      }
    }
    ghr0 += __shfl_xor(ghr0, 1); ghr0 += __shfl_xor(ghr0, 2);
    ghz0 += __shfl_xor(ghz0, 1); ghz0 += __shfl_xor(ghz0, 2);
    ghn0 += __shfl_xor(ghn0, 1); ghn0 += __shfl_xor(ghn0, 2);
    ghr1 += __shfl_xor(ghr1, 1); ghr1 += __shfl_xor(ghr1, 2);
    ghz1 += __shfl_xor(ghz1, 1); ghz1 += __shfl_xor(ghz1, 2);
    ghn1 += __shfl_xor(ghn1, 1); ghn1 += __shfl_xor(ghn1, 2);
    air0 += __shfl_xor(air0, 1); air0 += __shfl_xor(air0, 2);
    aiz0 += __shfl_xor(aiz0, 1); aiz0 += __shfl_xor(aiz0, 2);
    ain0 += __shfl_xor(ain0, 1); ain0 += __shfl_xor(ain0, 2);
    air1 += __shfl_xor(air1, 1); air1 += __shfl_xor(air1, 2);
    aiz1 += __shfl_xor(aiz1, 1); aiz1 += __shfl_xor(aiz1, 2);
    ain1 += __shfl_xor(ain1, 1); ain1 += __shfl_xor(ain1, 2);
    {
      double gir = (ROW ? air1 : air0) + (double)b_ih[O];
      double giz = (ROW ? aiz1 : aiz0) + (double)b_ih[256 + O];
      double gin = (ROW ? ain1 : ain0) + (double)b_ih[512 + O];
      double hr_ = (ROW ? ghr1 : ghr0) + (double)b_hh[O];
      double hz_ = (ROW ? ghz1 : ghz0) + (double)b_hh[256 + O];
      double hn_ = (ROW ? ghn1 : ghn0) + (double)b_hh[512 + O];
      double rr = 1.0 / (1.0 + exp(-(gir + hr_)));
      double zz = 1.0 / (1.0 + exp(-(giz + hz_)));
      double nn = tanh(gin + rr * hn_);
      double hold = hS[cur][ROW][PD(O)];
      double hnew = (1.0 - zz) * nn + zz * hold;
      if ((S & 1) == 0) hS[nxt][ROW][PD(O)] = hnew;
    }
    __syncthreads();  // B1: h ready

    // ---- P2: qk = Wqk·h + bqk ----
    {
      double q0 = 0, q1 = 0;
#pragma unroll 4
      for (int k = 0; k < 32; ++k) {
        double2 wv = Wp2[(WV * 32 + k) * 64 + LN];
        int dd = S * 64 + 2 * k;  // PD(dd) = dd + S
        const double* h0 = &hS[nxt][0][dd + S];
        const double* h1 = &hS[nxt][1][dd + S];
        q0 += wv.x * h0[0] + wv.y * h0[1];
        q1 += wv.x * h1[0] + wv.y * h1[1];
      }
      q0 += __shfl_xor(q0, 1); q0 += __shfl_xor(q0, 2);
      q1 += __shfl_xor(q1, 1); q1 += __shfl_xor(q1, 2);
      if (S == 0) {
        double bb = bqk[O];
        qs[0][PD(O)] = q0 + bb;
        qs[1][PD(O)] = q1 + bb;
      }
    }
    __syncthreads();  // B2: qs ready

    // ---- P3: logits + wave argmax ----
    double lgv0, lgv1;
    {
      double p0 = 0, p1 = 0;
#pragma unroll 2
      for (int k = 0; k < 16; ++k) {
        int eb = (WV * 16 + k) * 64 + LN;
        v4f e0 = ntload4(eP0 + eb);
        v4f e1 = ntload4(eP1 + eb);
        int c = S * 64 + 4 * k;
        const double* qa = &qs[0][c + S];
        const double* qb = &qs[1][c + S];
#pragma unroll
        for (int i = 0; i < 4; ++i) {
          p0 += (double)e0[i] * qa[i];
          p1 += (double)e1[i] * qb[i];
        }
      }
      p0 += __shfl_xor(p0, 1); p0 += __shfl_xor(p0, 2);
      p1 += __shfl_xor(p1, 1); p1 += __shfl_xor(p1, 2);
      lgv0 = 0.0625 * p0; if (!maskS[0][O]) lgv0 = NEGINF;
      lgv1 = 0.0625 * p1; if (!maskS[1][O]) lgv1 = NEGINF;
      if (S == 0) { lg[0][O] = lgv0; lg[1][O] = lgv1; }
      double v0 = lgv0, v1 = lgv1;
      int i0 = O, i1 = O;
#pragma unroll
      for (int off = 1; off < 64; off <<= 1) {
        double t0 = __shfl_xor(v0, off); int ti0 = __shfl_xor(i0, off);
        if (t0 > v0 || (t0 == v0 && ti0 < i0)) { v0 = t0; i0 = ti0; }
        double t1 = __shfl_xor(v1, off); int ti1 = __shfl_xor(i1, off);
        if (t1 > v1 || (t1 == v1 && ti1 < i1)) { v1 = t1; i1 = ti1; }
      }
      if (LN == 0) { redA[WV][0] = v0; redI[WV][0] = i0; redA[WV][1] = v1; redI[WV][1] = i1; }
    }
    __syncthreads();  // B3: redA ready

    // ---- P4: final max/argmax (all threads), exp-sums, gather next x ----
    double m0 = -1e300, m1 = -1e300;
    int am0 = 0, am1 = 0;
#pragma unroll 4
    for (int w = 0; w < 16; ++w) {
      double va = redA[w][0]; int ia = redI[w][0];
      if (va > m0 || (va == m0 && ia < am0)) { m0 = va; am0 = ia; }
      double vb = redA[w][1]; int ib = redI[w][1];
      if (vb > m1 || (vb == m1 && ib < am1)) { m1 = vb; am1 = ib; }
    }
    {
      double e0 = (S == 0) ? exp(lgv0 - m0) : 0.0;
      double e1 = (S == 0) ? exp(lgv1 - m1) : 0.0;
      double s20 = e0 * (lgv0 - m0);
      double s21 = e1 * (lgv1 - m1);
#pragma unroll
      for (int off = 1; off < 64; off <<= 1) {
        e0 += __shfl_xor(e0, off);
        e1 += __shfl_xor(e1, off);
        s20 += __shfl_xor(s20, off);
        s21 += __shfl_xor(s21, off);
      }
      if (LN == 0) { redB[WV][0] = e0; redB[WV][1] = e1; redC[WV][0] = s20; redC[WV][1] = s21; }
    }
    // gather next x from encP (L3-resident), scattered per packed layout
    if (tid < 512) {
      int r = tid >> 8, j = tid & 255;
      int am = r ? am1 : am0;
      int c4 = j >> 2;
      int vidx = ((am >> 4) * 16 + (c4 & 15)) * 64 + (4 * (am & 15) + (c4 >> 4));
      const float* ePr = r ? (const float*)eP1 : (const float*)eP0;
      xS[r][PD(j)] = (double)__builtin_nontemporal_load(ePr + vidx * 4 + (j & 3));
    }
    __syncthreads();  // B4: redB/C + x-gather ready

    // ---- P5: outputs + mask ----
    if (tid < 2) {
      int r = tid;
      double m = r ? m1 : m0;
      int am = r ? am1 : am0;
      double S1 = 0, S2 = 0;
#pragma unroll 4
      for (int w = 0; w < 16; ++w) { S1 += redB[w][r]; S2 += redC[w][r]; }
      double lS = log(S1);
      double logZ = m + lS;
      size_t row = (size_t)(b0 + r) * N_;
      out[row + t] = (float)am;
      out[(size_t)B_ * N_ + row + t] = (float)(lg[r][am] - logZ);
      out[2 * (size_t)B_ * N_ + row + t] = (float)(lS - S2 / S1);
      maskS[r][am] = 0;
    }
    __syncthreads();  // B5: mask/outputs done
    cur ^= 1;
  }
}

extern "C" void kernel_launch(void* const* d_in, const int* in_sizes, int n_in,
                              void* d_out, int out_size, void* d_ws, size_t ws_size,
                              hipStream_t stream) {
  const float* enc = (const float*)d_in[0];
  const float* init_token = (const float*)d_in[1];
  const float* w_ih = (const float*)d_in[2];
  const float* w_hh = (const float*)d_in[3];
  const float* b_ih = (const float*)d_in[4];
  const float* b_hh = (const float*)d_in[5];
  const float* wq = (const float*)d_in[6];
  const float* bq = (const float*)d_in[7];
  const float* wk = (const float*)d_in[8];
  const float* bk = (const float*)d_in[9];  // folded out by softmax shift-invariance
  (void)bk;
  float* out = (float*)d_out;
  char* wsb = (char*)d_ws;

  // ws layout (bytes)
  float* wihP = (float*)(wsb + 0);          //    786,432
  float* whhP = (float*)(wsb + 786432);     //    786,432
  double* WqkP = (double*)(wsb + 1572864);  //    524,288
  double* bqk = (double*)(wsb + 2097152);   //      2,048
  float* encP = (float*)(wsb + 2099200);    // 134,217,728  (end: 136,316,928)

  hipLaunchKernelGGL(packW_k, dim3(192), dim3(256), 0, stream, w_ih, wihP);
  hipLaunchKernelGGL(packW_k, dim3(192), dim3(256), 0, stream, w_hh, whhP);
  hipLaunchKernelGGL(wqk_k, dim3(256), dim3(256), 0, stream, wk, wq, bq, WqkP, bqk);
  hipLaunchKernelGGL(encp_k, dim3(64, 512), dim3(256), 0, stream, enc, encP);
  hipLaunchKernelGGL(decode_k, dim3(B_ / 2), dim3(1024), 0, stream, enc, init_token,
                     b_ih, b_hh, wihP, whhP, WqkP, bqk, encP, out);
}